// Round 1
// baseline (83.256 us; speedup 1.0000x reference)
//
#include <hip/hip_runtime.h>
#include <cmath>

#define BB 8
#define MM 32
#define CC 80
#define AA 65536  // GRID*GRID*4

__global__ __launch_bounds__(256) void det_main(
    const float* __restrict__ logits,
    const float* __restrict__ anchors,
    const float* __restrict__ boxes,
    const int* __restrict__ labels_idx,
    float* __restrict__ out,   // [0]=loss (filled by finalize), [1 .. B*A]=conf, [1+B*A ..]=targets(as float)
    float* __restrict__ ws)    // ws[0]=loss_sum, ws[1]=num_pos
{
    __shared__ float s_boxes[MM * 4];
    __shared__ int   s_lab[MM];
    __shared__ float s_red[256];
    __shared__ float s_red2[256];

    const int b = blockIdx.x >> 8;                       // 256 blocks per batch (65536/256)
    const int a = ((blockIdx.x & 255) << 8) | threadIdx.x;

    if (threadIdx.x < MM * 4) s_boxes[threadIdx.x] = boxes[b * MM * 4 + threadIdx.x];
    if (threadIdx.x < MM)     s_lab[threadIdx.x]   = labels_idx[b * MM + threadIdx.x];
    __syncthreads();

    // ---- IoU assignment (anchor a vs 32 boxes of batch b) ----
    const float4 anc = ((const float4*)anchors)[a];
    const float area_a = (anc.z - anc.x) * (anc.w - anc.y);
    float max_iou = -1.0f;
    int   assign  = 0;
    #pragma unroll
    for (int m = 0; m < MM; ++m) {
        const float bx1 = s_boxes[m * 4 + 0], by1 = s_boxes[m * 4 + 1];
        const float bx2 = s_boxes[m * 4 + 2], by2 = s_boxes[m * 4 + 3];
        const float ltx = fmaxf(anc.x, bx1), lty = fmaxf(anc.y, by1);
        const float rbx = fminf(anc.z, bx2), rby = fminf(anc.w, by2);
        const float w = fmaxf(rbx - ltx, 0.0f);
        const float h = fmaxf(rby - lty, 0.0f);
        const float inter = w * h;
        const float area_b = (bx2 - bx1) * (by2 - by1);
        const float uni = area_a + area_b - inter;
        const float iou = (uni > 0.0f) ? inter / uni : 0.0f;
        if (iou > max_iou) { max_iou = iou; assign = m; }  // first-max semantics (strict >)
    }
    const bool pos     = (max_iou >= 0.5f);
    const bool neg     = (max_iou < 0.1f);
    const bool labeled = pos || neg;
    const int  tc      = pos ? s_lab[assign] : -1;

    // ---- stream the 80-logit row: max/argmax + focal BCE sum ----
    const float4* row = (const float4*)(logits + ((size_t)b * AA + (size_t)a) * CC);
    float mx = -INFINITY;
    int   amx = 0;
    float loss = 0.0f;
    #pragma unroll
    for (int k = 0; k < CC / 4; ++k) {
        const float4 v = row[k];
        const float lv[4] = {v.x, v.y, v.z, v.w};
        #pragma unroll
        for (int j = 0; j < 4; ++j) {
            const int c = k * 4 + j;
            const float l = lv[j];
            if (l > mx) { mx = l; amx = c; }
            const float t  = (c == tc) ? 1.0f : 0.0f;
            const float e  = __expf(-fabsf(l));
            const float sp = fmaxf(l, 0.0f) - l * t + logf(1.0f + e);  // BCE
            const float p  = 1.0f / (1.0f + __expf(-l));               // sigmoid
            const float d  = t - p;
            loss += sp * d * d;                                        // focal-weighted
        }
    }

    const size_t ba = (size_t)b * AA + (size_t)a;
    out[1 + ba] = 1.0f / (1.0f + __expf(-mx));                 // max prob = sigmoid(max logit)
    out[1 + (size_t)BB * AA + ba] = (float)amx;                // argmax index as float

    // ---- block reduce {labeled loss, pos count} ----
    s_red[threadIdx.x]  = labeled ? loss : 0.0f;
    s_red2[threadIdx.x] = pos ? 1.0f : 0.0f;
    __syncthreads();
    #pragma unroll
    for (int s = 128; s > 0; s >>= 1) {
        if (threadIdx.x < s) {
            s_red[threadIdx.x]  += s_red[threadIdx.x + s];
            s_red2[threadIdx.x] += s_red2[threadIdx.x + s];
        }
        __syncthreads();
    }
    if (threadIdx.x == 0) {
        atomicAdd(&ws[0], s_red[0]);
        atomicAdd(&ws[1], s_red2[0]);
    }
}

__global__ void det_final(const float* __restrict__ ws, float* __restrict__ out) {
    out[0] = ws[0] / ws[1];
}

extern "C" void kernel_launch(void* const* d_in, const int* in_sizes, int n_in,
                              void* d_out, int out_size, void* d_ws, size_t ws_size,
                              hipStream_t stream) {
    const float* logits     = (const float*)d_in[0];
    const float* anchors    = (const float*)d_in[1];
    const float* boxes      = (const float*)d_in[2];
    // d_in[3] (one-hot labels) unused: gathered one-hot == one-hot(labels_idx[assign])
    const int*   labels_idx = (const int*)d_in[4];
    float* out = (float*)d_out;
    float* ws  = (float*)d_ws;

    hipMemsetAsync(ws, 0, 2 * sizeof(float), stream);
    det_main<<<dim3((BB * AA) / 256), dim3(256), 0, stream>>>(logits, anchors, boxes, labels_idx, out, ws);
    det_final<<<1, 1, 0, stream>>>(ws, out);
}